// Round 6
// baseline (37649.051 us; speedup 1.0000x reference)
//
#include <hip/hip_runtime.h>
#include <hip/hip_cooperative_groups.h>
#include <math.h>

namespace cg = cooperative_groups;

namespace {
constexpr int BATCH = 128;
constexpr int SEQ   = 512;
constexpr int NL    = 32;
constexpr int BOSTAG = 1;
constexpr int EOSTAG = 2;
}

// hbuf layout: [2 parity][2 dir][128 b][512 u]  (65536 floats per (par,dir))
__global__ __launch_bounds__(512, 1)
void bilstm_coop(const int* __restrict__ x,
                 const float* __restrict__ emb,
                 const float* __restrict__ Wih_f, const float* __restrict__ Whh_f, const float* __restrict__ bf,
                 const float* __restrict__ Wih_b, const float* __restrict__ Whh_b, const float* __restrict__ bbias,
                 const float* __restrict__ Wout, const float* __restrict__ bout,
                 float* __restrict__ hbuf, float* __restrict__ em)
{
  cg::grid_group grid = cg::this_grid();
  __shared__ float4 WT4[8192];     // [k(1024)][slot(8)] gates in .xyzw; slot = uu ^ ((k>>2)&7). 128 KB
  __shared__ float  em_red[512];   // [eks(16)][l(32)]

  const int tid = threadIdx.x, bi = blockIdx.x;
  const int dir = bi >> 7, bidx = bi & 127;
  const int ug  = bidx >> 1, bh = bidx & 1;    // ug: 8-unit slice, bh: batch half
  const int u0  = ug * 8, b_base = bh * 64;
  const int bb  = b_base + ug;                 // emission batch owned by this block

  const float* Wih = dir ? Wih_b : Wih_f;
  const float* Whh = dir ? Whh_b : Whh_f;
  const float* bv  = dir ? bbias : bf;

  // ---- one-time: W slice -> LDS. WT4[k*8+slot] = gates(i,f,g,o) of unit uu=slot^((k>>2)&7)
  for (int idx = tid; idx < 8192; idx += 512) {
    const int k = idx >> 3, slot = idx & 7;
    const int uu = slot ^ ((k >> 2) & 7);
    float4 v;
    if (k < 512) {
      v.x = Wih[(size_t)(0 * 512 + u0 + uu) * 512 + k];
      v.y = Wih[(size_t)(1 * 512 + u0 + uu) * 512 + k];
      v.z = Wih[(size_t)(2 * 512 + u0 + uu) * 512 + k];
      v.w = Wih[(size_t)(3 * 512 + u0 + uu) * 512 + k];
    } else {
      v.x = Whh[(size_t)(0 * 512 + u0 + uu) * 512 + (k - 512)];
      v.y = Whh[(size_t)(1 * 512 + u0 + uu) * 512 + (k - 512)];
      v.z = Whh[(size_t)(2 * 512 + u0 + uu) * 512 + (k - 512)];
      v.w = Whh[(size_t)(3 * 512 + u0 + uu) * 512 + (k - 512)];
    }
    WT4[idx] = v;
  }

  // compute mapping: thread = (ks: in-wave k-split, uo: unit, rt: wave batch-octet)
  const int ks = tid & 7;           // k-split lane (butterfly xor 1,2,4)
  const int uo = (tid >> 3) & 7;    // owned unit u0+uo
  const int rt = tid >> 6;          // wave index = batch octet rt*8..rt*8+7
  const int wslot = uo ^ ks;        // swz(k)=ks for this thread's k-set -> constant slot
  const int bown8 = b_base + rt * 8;
  // emission mapping
  const int el = tid & 31, eks = tid >> 5;   // label, k-split of 16 (32 k each)

  float bias_g[4];
  #pragma unroll
  for (int g = 0; g < 4; ++g) bias_g[g] = bv[g * 512 + u0 + uo];
  float cstate = 0.f;

  // zero parity-1 h (initial state)
  hbuf[131072 + bi * 512 + tid] = 0.f;
  grid.sync();

  for (int s = 0; s < SEQ; ++s) {
    const int t = dir ? (SEQ - 1 - s) : s;
    // pre-sync: embedding row offsets for this wave's 8 batches
    int xo[8];
    #pragma unroll
    for (int q = 0; q < 8; ++q) xo[q] = x[(bown8 + q) * SEQ + t] << 9;

    grid.sync();

    const float* hprev = hbuf + (size_t)((s + 1) & 1) * 131072 + dir * 65536;
    float*       hout  = hbuf + (size_t)((s    ) & 1) * 131072 + dir * 65536;

    // ---- emission for h_{s-1} (transient regs, before acc goes live) ----
    if (s > 0) {
      const float* wr_ = Wout + (size_t)el * 1024 + dir * 512 + eks * 32;
      const float* hb2 = hprev + (size_t)bb * 512 + eks * 32;
      float emP = 0.f;
      #pragma unroll
      for (int q = 0; q < 8; ++q) {
        const float4 wv = *(const float4*)&wr_[q * 4];
        const float4 hv = *(const float4*)&hb2[q * 4];
        emP = fmaf(hv.x, wv.x, emP);
        emP = fmaf(hv.y, wv.y, emP);
        emP = fmaf(hv.z, wv.z, emP);
        emP = fmaf(hv.w, wv.w, emP);
      }
      em_red[eks * 32 + el] = emP;
    }
    __syncthreads();
    if (s > 0 && tid < 32) {
      float p = 0.f;
      #pragma unroll
      for (int ksi = 0; ksi < 16; ++ksi) p += em_red[ksi * 32 + tid];
      const int te = dir ? (SEQ - s) : (s - 1);
      const bool first = dir ? (te >= 256) : (te < 256);
      float* dst = em + ((size_t)bb * SEQ + te) * NL + tid;
      if (first) *dst = p + bout[tid];
      else       *dst = *dst + p;
    }

    // ---- gate GEMM: acc[gate][q], one W ds_read_b128 per k, 32 FMA per read ----
    float acc[4][8];
    #pragma unroll
    for (int g = 0; g < 4; ++g)
      #pragma unroll
      for (int q = 0; q < 8; ++q) acc[g][q] = 0.f;

    // emb half: k = ks*4 + 32 i + j
    #pragma unroll 4
    for (int i = 0; i < 16; ++i) {
      float4 A[8];
      #pragma unroll
      for (int q = 0; q < 8; ++q)
        A[q] = *(const float4*)&emb[xo[q] + i * 32 + ks * 4];
      #pragma unroll
      for (int j = 0; j < 4; ++j) {
        const float4 w4 = WT4[(size_t)(i * 32 + ks * 4 + j) * 8 + wslot];
        #pragma unroll
        for (int q = 0; q < 8; ++q) {
          const float a = (j == 0) ? A[q].x : (j == 1) ? A[q].y : (j == 2) ? A[q].z : A[q].w;
          acc[0][q] = fmaf(w4.x, a, acc[0][q]);
          acc[1][q] = fmaf(w4.y, a, acc[1][q]);
          acc[2][q] = fmaf(w4.z, a, acc[2][q]);
          acc[3][q] = fmaf(w4.w, a, acc[3][q]);
        }
      }
    }
    // h half: k = 512 + ks*4 + 32 i + j
    #pragma unroll 4
    for (int i = 0; i < 16; ++i) {
      float4 A[8];
      #pragma unroll
      for (int q = 0; q < 8; ++q)
        A[q] = *(const float4*)&hprev[(size_t)(bown8 + q) * 512 + i * 32 + ks * 4];
      #pragma unroll
      for (int j = 0; j < 4; ++j) {
        const float4 w4 = WT4[(size_t)(512 + i * 32 + ks * 4 + j) * 8 + wslot];
        #pragma unroll
        for (int q = 0; q < 8; ++q) {
          const float a = (j == 0) ? A[q].x : (j == 1) ? A[q].y : (j == 2) ? A[q].z : A[q].w;
          acc[0][q] = fmaf(w4.x, a, acc[0][q]);
          acc[1][q] = fmaf(w4.y, a, acc[1][q]);
          acc[2][q] = fmaf(w4.z, a, acc[2][q]);
          acc[3][q] = fmaf(w4.w, a, acc[3][q]);
        }
      }
    }

    // ---- butterfly over the 8 ks lanes (in-wave xor 1,2,4) ----
    #pragma unroll
    for (int m = 1; m < 8; m <<= 1)
      #pragma unroll
      for (int g = 0; g < 4; ++g)
        #pragma unroll
        for (int q = 0; q < 8; ++q)
          acc[g][q] += __shfl_xor(acc[g][q], m, 64);

    // lane ks owns batch bown8+ks, unit u0+uo: static select q = ks
    {
      float g4[4];
      #pragma unroll
      for (int g = 0; g < 4; ++g) {
        float v = acc[g][0];
        v = (ks == 1) ? acc[g][1] : v;
        v = (ks == 2) ? acc[g][2] : v;
        v = (ks == 3) ? acc[g][3] : v;
        v = (ks == 4) ? acc[g][4] : v;
        v = (ks == 5) ? acc[g][5] : v;
        v = (ks == 6) ? acc[g][6] : v;
        v = (ks == 7) ? acc[g][7] : v;
        g4[g] = v;
      }
      const float gi = g4[0] + bias_g[0];
      const float gf = g4[1] + bias_g[1];
      const float gg = g4[2] + bias_g[2];
      const float go = g4[3] + bias_g[3];
      const float si = 1.f / (1.f + expf(-gi));
      const float sf = 1.f / (1.f + expf(-gf));
      const float so = 1.f / (1.f + expf(-go));
      cstate = sf * cstate + si * tanhf(gg);
      hout[(size_t)(bown8 + ks) * 512 + u0 + uo] = so * tanhf(cstate);
    }
  }
  grid.sync();

  // ---- tail emission for the last h (parity 1) ----
  {
    const float* wr_ = Wout + (size_t)el * 1024 + dir * 512 + eks * 32;
    const float* hb2 = hbuf + 131072 + dir * 65536 + (size_t)bb * 512 + eks * 32;
    float emP = 0.f;
    #pragma unroll
    for (int q = 0; q < 8; ++q) {
      const float4 wv = *(const float4*)&wr_[q * 4];
      const float4 hv = *(const float4*)&hb2[q * 4];
      emP = fmaf(hv.x, wv.x, emP);
      emP = fmaf(hv.y, wv.y, emP);
      emP = fmaf(hv.z, wv.z, emP);
      emP = fmaf(hv.w, wv.w, emP);
    }
    em_red[eks * 32 + el] = emP;
    __syncthreads();
    if (tid < 32) {
      float p = 0.f;
      #pragma unroll
      for (int ksi = 0; ksi < 16; ++ksi) p += em_red[ksi * 32 + tid];
      const int te = dir ? 0 : (SEQ - 1);
      float* dst = em + ((size_t)bb * SEQ + te) * NL + tid;
      *dst = *dst + p;
    }
  }
}

__global__ __launch_bounds__(64)
void viterbi_kernel(const float* __restrict__ em, const int* __restrict__ mask,
                    const float* __restrict__ trans, float* __restrict__ out)
{
  __shared__ float tr[32][33];
  __shared__ float alpha[32];
  __shared__ float fin[32];
  __shared__ unsigned char bp[SEQ][32];
  __shared__ float path[SEQ];

  const int b = blockIdx.x, tid = threadIdx.x;
  for (int i = tid; i < 1024; i += 64) tr[i >> 5][i & 31] = trans[i];
  __syncthreads();

  const float* emB = em + (size_t)b * SEQ * NL;
  if (tid < 32) alpha[tid] = tr[BOSTAG][tid] + emB[tid];
  __syncthreads();

  for (int t = 1; t < SEQ; ++t) {
    float best = -INFINITY, e = 0.f;
    int arg = 0;
    if (tid < 32) {
      e = emB[t * NL + tid];
      #pragma unroll 4
      for (int p = 0; p < 32; ++p) {
        const float sc = (alpha[p] + tr[p][tid]) + e;  // np broadcast order
        if (sc > best) { best = sc; arg = p; }          // first-occurrence argmax
      }
    }
    __syncthreads();
    if (tid < 32) {
      const float m = (float)mask[b * SEQ + t];
      alpha[tid] = m * best + (1.f - m) * alpha[tid];
      bp[t][tid] = (unsigned char)arg;
    }
    __syncthreads();
  }

  if (tid < 32) fin[tid] = alpha[tid] + tr[tid][EOSTAG];
  __syncthreads();

  if (tid == 0) {
    float best = fin[0]; int tag = 0;
    for (int n = 1; n < 32; ++n) if (fin[n] > best) { best = fin[n]; tag = n; }
    out[b] = best;
    path[SEQ - 1] = (float)tag;
    for (int k = SEQ - 2; k >= 0; --k) {
      const int prev = bp[k + 1][tag];
      if (mask[b * SEQ + k + 1] > 0) tag = prev;
      path[k] = (float)tag;
    }
  }
  __syncthreads();
  for (int idx = tid; idx < SEQ; idx += 64)
    out[BATCH + (size_t)b * SEQ + idx] = path[idx];
}

extern "C" void kernel_launch(void* const* d_in, const int* in_sizes, int n_in,
                              void* d_out, int out_size, void* d_ws, size_t ws_size,
                              hipStream_t stream) {
  (void)in_sizes; (void)n_in; (void)out_size; (void)ws_size;
  const int*   x     = (const int*)d_in[0];
  const int*   mask  = (const int*)d_in[1];
  const float* emb   = (const float*)d_in[2];
  const float* Wih_f = (const float*)d_in[3];
  const float* Whh_f = (const float*)d_in[4];
  const float* bf    = (const float*)d_in[5];
  const float* Wih_b = (const float*)d_in[6];
  const float* Whh_b = (const float*)d_in[7];
  const float* bb    = (const float*)d_in[8];
  const float* Wout  = (const float*)d_in[9];
  const float* bout  = (const float*)d_in[10];
  const float* trans = (const float*)d_in[11];
  float* out  = (float*)d_out;
  float* hbuf = (float*)d_ws;                   // 262144 floats (1 MB)
  float* em   = hbuf + 262144;                  // 2097152 floats (8 MB)

  void* args[] = { (void*)&x, (void*)&emb,
                   (void*)&Wih_f, (void*)&Whh_f, (void*)&bf,
                   (void*)&Wih_b, (void*)&Whh_b, (void*)&bb,
                   (void*)&Wout, (void*)&bout,
                   (void*)&hbuf, (void*)&em };
  hipLaunchCooperativeKernel((void*)bilstm_coop, dim3(256), dim3(512), args, 0, stream);
  viterbi_kernel<<<dim3(128), dim3(64), 0, stream>>>(em, mask, trans, out);
}

// Round 7
// 27138.721 us; speedup vs baseline: 1.3873x; 1.3873x over previous
//
#include <hip/hip_runtime.h>
#include <math.h>

namespace {
constexpr int BATCH = 128;
constexpr int SEQ   = 512;
constexpr int NL    = 32;
constexpr int BOSTAG = 1;
constexpr int EOSTAG = 2;
constexpr unsigned NBLK = 256;
}

__device__ unsigned int g_cnt;

__global__ void reset_cnt_kernel() {
  __hip_atomic_store(&g_cnt, 0u, __ATOMIC_RELAXED, __HIP_MEMORY_SCOPE_AGENT);
}

// Lightweight grid barrier. Preconditions: all cross-block-visible stores in the
// step are agent-scope write-through (reach L3/coherence point; drained by the
// vmcnt(0) the compiler emits before s_barrier). Release: counter add (relaxed,
// agent). Acquire: spin + fence(acquire,"agent") -> invalidates L1/L2 so plain
// cached reads refetch fresh lines from L3. Early-fence by racing waves is safe:
// between inv and release nobody can re-cache stale lines of the parity being
// flipped (writers are write-through/no-allocate; readers only read post-release).
__device__ __forceinline__ void gbar(unsigned target) {
  __syncthreads();
  if (threadIdx.x == 0) {
    __hip_atomic_fetch_add(&g_cnt, 1u, __ATOMIC_RELAXED, __HIP_MEMORY_SCOPE_AGENT);
    while (__hip_atomic_load(&g_cnt, __ATOMIC_RELAXED, __HIP_MEMORY_SCOPE_AGENT) < target)
      __builtin_amdgcn_s_sleep(2);
  }
  __builtin_amdgcn_fence(__ATOMIC_ACQUIRE, "agent");
  __syncthreads();
}

// hbuf layout: [2 parity][2 dir][128 b][512 u]  (65536 floats per (par,dir))
__global__ __launch_bounds__(512, 2)
void bilstm_coop(const int* __restrict__ x,
                 const float* __restrict__ emb,
                 const float* __restrict__ Wih_f, const float* __restrict__ Whh_f, const float* __restrict__ bf,
                 const float* __restrict__ Wih_b, const float* __restrict__ Whh_b, const float* __restrict__ bbias,
                 const float* __restrict__ Wout, const float* __restrict__ bout,
                 float* __restrict__ hbuf, float* __restrict__ em)
{
  __shared__ float4 WT4[8192];     // [k(1024)][slot(8)] gates in .xyzw; slot = uu ^ ((k>>2)&7). 128 KB
  __shared__ float  em_red[512];   // [eks(16)][l(32)]

  const int tid = threadIdx.x, bi = blockIdx.x;
  const int dir = bi >> 7, bidx = bi & 127;
  const int ug  = bidx >> 1, bh = bidx & 1;    // ug: 8-unit slice, bh: batch half
  const int u0  = ug * 8, b_base = bh * 64;
  const int bb  = b_base + ug;                 // emission batch owned by this block

  const float* Wih = dir ? Wih_b : Wih_f;
  const float* Whh = dir ? Whh_b : Whh_f;
  const float* bv  = dir ? bbias : bf;

  // ---- one-time: W slice -> LDS. WT4[k*8+slot] = gates(i,f,g,o) of unit uu=slot^((k>>2)&7)
  for (int idx = tid; idx < 8192; idx += 512) {
    const int k = idx >> 3, slot = idx & 7;
    const int uu = slot ^ ((k >> 2) & 7);
    float4 v;
    if (k < 512) {
      v.x = Wih[(size_t)(0 * 512 + u0 + uu) * 512 + k];
      v.y = Wih[(size_t)(1 * 512 + u0 + uu) * 512 + k];
      v.z = Wih[(size_t)(2 * 512 + u0 + uu) * 512 + k];
      v.w = Wih[(size_t)(3 * 512 + u0 + uu) * 512 + k];
    } else {
      v.x = Whh[(size_t)(0 * 512 + u0 + uu) * 512 + (k - 512)];
      v.y = Whh[(size_t)(1 * 512 + u0 + uu) * 512 + (k - 512)];
      v.z = Whh[(size_t)(2 * 512 + u0 + uu) * 512 + (k - 512)];
      v.w = Whh[(size_t)(3 * 512 + u0 + uu) * 512 + (k - 512)];
    }
    WT4[idx] = v;
  }

  // compute mapping: thread = (ks in-wave k-split, bown batch)
  const int ks   = tid & 7;
  const int bown = tid >> 3;
  const int bg   = b_base + bown;
  // emission mapping
  const int el = tid & 31, eks = tid >> 5;     // label, k-split of 16 (32 k each)

  float bias_g[4];
  #pragma unroll
  for (int g = 0; g < 4; ++g) bias_g[g] = bv[g * 512 + u0 + ks];
  float cstate = 0.f;

  // zero parity-1 h (initial state) -- write-through so all blocks see it
  __hip_atomic_store(&hbuf[131072 + bi * 512 + tid], 0.f,
                     __ATOMIC_RELAXED, __HIP_MEMORY_SCOPE_AGENT);
  unsigned epoch = 1;
  gbar(NBLK * epoch); ++epoch;

  for (int s = 0; s < SEQ; ++s) {
    const int t = dir ? (SEQ - 1 - s) : s;
    // pre-barrier: read-only prefetch (x, first emb float4)
    const int    xid  = x[bg * SEQ + t];
    const float* erow = emb + (size_t)xid * 512 + ks * 4;
    float4 aP = *(const float4*)erow;

    gbar(NBLK * epoch); ++epoch;

    const float* hprev = hbuf + (size_t)((s + 1) & 1) * 131072 + dir * 65536;
    float*       hout  = hbuf + (size_t)((s    ) & 1) * 131072 + dir * 65536;
    const float* hrow  = hprev + (size_t)bg * 512 + ks * 4;

    // ---- emission for h_{s-1}: burst-issue h loads (L3), then Wout (L2-hot) ----
    if (s > 0) {
      const float* hb2 = hprev + (size_t)bb * 512 + eks * 32;
      float4 hv[8], wv[8];
      #pragma unroll
      for (int q = 0; q < 8; ++q) hv[q] = *(const float4*)&hb2[q * 4];
      const float* wr_ = Wout + (size_t)el * 1024 + dir * 512 + eks * 32;
      #pragma unroll
      for (int q = 0; q < 8; ++q) wv[q] = *(const float4*)&wr_[q * 4];
      float emP = 0.f;
      #pragma unroll
      for (int q = 0; q < 8; ++q) {
        emP = fmaf(hv[q].x, wv[q].x, emP);
        emP = fmaf(hv[q].y, wv[q].y, emP);
        emP = fmaf(hv[q].z, wv[q].z, emP);
        emP = fmaf(hv[q].w, wv[q].w, emP);
      }
      em_red[eks * 32 + el] = emP;
    }
    __syncthreads();
    if (s > 0 && tid < 32) {
      float p = 0.f;
      #pragma unroll
      for (int ksi = 0; ksi < 16; ++ksi) p += em_red[ksi * 32 + tid];
      const int te = dir ? (SEQ - s) : (s - 1);
      const bool first = dir ? (te >= 256) : (te < 256);
      float* dst = em + ((size_t)bb * SEQ + te) * NL + tid;
      if (first) {
        __hip_atomic_store(dst, p + bout[tid], __ATOMIC_RELAXED, __HIP_MEMORY_SCOPE_AGENT);
      } else {
        const float old = *dst;   // fresh: producer wrote-through, fences since
        __hip_atomic_store(dst, old + p, __ATOMIC_RELAXED, __HIP_MEMORY_SCOPE_AGENT);
      }
    }

    // ---- gate GEMM: acc[uu][g], k-split over 8 in-wave lanes ----
    float acc[8][4];
    #pragma unroll
    for (int uu = 0; uu < 8; ++uu)
      #pragma unroll
      for (int g = 0; g < 4; ++g) acc[uu][g] = 0.f;

    // emb half: k = ks*4 + 32 i + j   (emb lines stay L2-cached across steps now)
    #pragma unroll 2
    for (int i = 0; i < 16; ++i) {
      const float4 aC = aP;
      const float* nx = (i < 15) ? (erow + 32 * (i + 1)) : hrow;
      aP = *(const float4*)nx;
      const float4* Wb = WT4 + (size_t)(ks * 4 + 32 * i) * 8;
      #pragma unroll
      for (int j = 0; j < 4; ++j) {
        const float a = (j == 0) ? aC.x : (j == 1) ? aC.y : (j == 2) ? aC.z : aC.w;
        const float4* Wk = Wb + j * 8;
        #pragma unroll
        for (int uu = 0; uu < 8; ++uu) {
          const float4 w4 = Wk[uu ^ ks];
          acc[uu][0] = fmaf(w4.x, a, acc[uu][0]);
          acc[uu][1] = fmaf(w4.y, a, acc[uu][1]);
          acc[uu][2] = fmaf(w4.z, a, acc[uu][2]);
          acc[uu][3] = fmaf(w4.w, a, acc[uu][3]);
        }
      }
    }
    // h half: k = 512 + ks*4 + 32 i + j; depth-4 ring hides L3 latency (~800cy)
    float4 ahr[4];
    #pragma unroll
    for (int p = 0; p < 4; ++p) ahr[p] = *(const float4*)(hrow + 32 * (1 + p));
    #pragma unroll 2
    for (int i = 0; i < 16; ++i) {
      const float4 aC = aP;
      aP = ahr[i & 3];
      if (i + 5 < 16) ahr[i & 3] = *(const float4*)(hrow + 32 * (i + 5));
      const float4* Wb = WT4 + (size_t)(512 + ks * 4 + 32 * i) * 8;
      #pragma unroll
      for (int j = 0; j < 4; ++j) {
        const float a = (j == 0) ? aC.x : (j == 1) ? aC.y : (j == 2) ? aC.z : aC.w;
        const float4* Wk = Wb + j * 8;
        #pragma unroll
        for (int uu = 0; uu < 8; ++uu) {
          const float4 w4 = Wk[uu ^ ks];
          acc[uu][0] = fmaf(w4.x, a, acc[uu][0]);
          acc[uu][1] = fmaf(w4.y, a, acc[uu][1]);
          acc[uu][2] = fmaf(w4.z, a, acc[uu][2]);
          acc[uu][3] = fmaf(w4.w, a, acc[uu][3]);
        }
      }
    }

    // ---- butterfly over the 8 ks lanes (in-wave xor 1,2,4) ----
    #pragma unroll
    for (int m = 1; m < 8; m <<= 1)
      #pragma unroll
      for (int uu = 0; uu < 8; ++uu)
        #pragma unroll
        for (int g = 0; g < 4; ++g)
          acc[uu][g] += __shfl_xor(acc[uu][g], m, 64);

    // lane ks owns unit u0+ks: static ternary select
    {
      float g4[4];
      #pragma unroll
      for (int g = 0; g < 4; ++g) {
        float v = acc[0][g];
        v = (ks == 1) ? acc[1][g] : v;
        v = (ks == 2) ? acc[2][g] : v;
        v = (ks == 3) ? acc[3][g] : v;
        v = (ks == 4) ? acc[4][g] : v;
        v = (ks == 5) ? acc[5][g] : v;
        v = (ks == 6) ? acc[6][g] : v;
        v = (ks == 7) ? acc[7][g] : v;
        g4[g] = v;
      }
      const float gi = g4[0] + bias_g[0];
      const float gf = g4[1] + bias_g[1];
      const float gg = g4[2] + bias_g[2];
      const float go = g4[3] + bias_g[3];
      const float si = 1.f / (1.f + expf(-gi));
      const float sf = 1.f / (1.f + expf(-gf));
      const float so = 1.f / (1.f + expf(-go));
      cstate = sf * cstate + si * tanhf(gg);
      // write-through so next step's cross-block reads see it after the barrier
      __hip_atomic_store(&hout[(size_t)bg * 512 + u0 + ks], so * tanhf(cstate),
                         __ATOMIC_RELAXED, __HIP_MEMORY_SCOPE_AGENT);
    }
  }
  gbar(NBLK * epoch); ++epoch;

  // ---- tail emission for the last h (parity 1) ----
  {
    const float* wr_ = Wout + (size_t)el * 1024 + dir * 512 + eks * 32;
    const float* hb2 = hbuf + 131072 + dir * 65536 + (size_t)bb * 512 + eks * 32;
    float emP = 0.f;
    #pragma unroll
    for (int q = 0; q < 8; ++q) {
      const float4 wv = *(const float4*)&wr_[q * 4];
      const float4 hv = *(const float4*)&hb2[q * 4];
      emP = fmaf(hv.x, wv.x, emP);
      emP = fmaf(hv.y, wv.y, emP);
      emP = fmaf(hv.z, wv.z, emP);
      emP = fmaf(hv.w, wv.w, emP);
    }
    em_red[eks * 32 + el] = emP;
    __syncthreads();
    if (tid < 32) {
      float p = 0.f;
      #pragma unroll
      for (int ksi = 0; ksi < 16; ++ksi) p += em_red[ksi * 32 + tid];
      const int te = dir ? 0 : (SEQ - 1);
      float* dst = em + ((size_t)bb * SEQ + te) * NL + tid;
      const float old = *dst;
      __hip_atomic_store(dst, old + p, __ATOMIC_RELAXED, __HIP_MEMORY_SCOPE_AGENT);
    }
  }
}

__global__ __launch_bounds__(64)
void viterbi_kernel(const float* __restrict__ em, const int* __restrict__ mask,
                    const float* __restrict__ trans, float* __restrict__ out)
{
  __shared__ float tr[32][33];
  __shared__ float alpha[32];
  __shared__ float fin[32];
  __shared__ unsigned char bp[SEQ][32];
  __shared__ float path[SEQ];

  const int b = blockIdx.x, tid = threadIdx.x;
  for (int i = tid; i < 1024; i += 64) tr[i >> 5][i & 31] = trans[i];
  __syncthreads();

  const float* emB = em + (size_t)b * SEQ * NL;
  if (tid < 32) alpha[tid] = tr[BOSTAG][tid] + emB[tid];
  __syncthreads();

  for (int t = 1; t < SEQ; ++t) {
    float best = -INFINITY, e = 0.f;
    int arg = 0;
    if (tid < 32) {
      e = emB[t * NL + tid];
      #pragma unroll 4
      for (int p = 0; p < 32; ++p) {
        const float sc = (alpha[p] + tr[p][tid]) + e;  // np broadcast order
        if (sc > best) { best = sc; arg = p; }          // first-occurrence argmax
      }
    }
    __syncthreads();
    if (tid < 32) {
      const float m = (float)mask[b * SEQ + t];
      alpha[tid] = m * best + (1.f - m) * alpha[tid];
      bp[t][tid] = (unsigned char)arg;
    }
    __syncthreads();
  }

  if (tid < 32) fin[tid] = alpha[tid] + tr[tid][EOSTAG];
  __syncthreads();

  if (tid == 0) {
    float best = fin[0]; int tag = 0;
    for (int n = 1; n < 32; ++n) if (fin[n] > best) { best = fin[n]; tag = n; }
    out[b] = best;
    path[SEQ - 1] = (float)tag;
    for (int k = SEQ - 2; k >= 0; --k) {
      const int prev = bp[k + 1][tag];
      if (mask[b * SEQ + k + 1] > 0) tag = prev;
      path[k] = (float)tag;
    }
  }
  __syncthreads();
  for (int idx = tid; idx < SEQ; idx += 64)
    out[BATCH + (size_t)b * SEQ + idx] = path[idx];
}

extern "C" void kernel_launch(void* const* d_in, const int* in_sizes, int n_in,
                              void* d_out, int out_size, void* d_ws, size_t ws_size,
                              hipStream_t stream) {
  (void)in_sizes; (void)n_in; (void)out_size; (void)ws_size;
  const int*   x     = (const int*)d_in[0];
  const int*   mask  = (const int*)d_in[1];
  const float* emb   = (const float*)d_in[2];
  const float* Wih_f = (const float*)d_in[3];
  const float* Whh_f = (const float*)d_in[4];
  const float* bf    = (const float*)d_in[5];
  const float* Wih_b = (const float*)d_in[6];
  const float* Whh_b = (const float*)d_in[7];
  const float* bb    = (const float*)d_in[8];
  const float* Wout  = (const float*)d_in[9];
  const float* bout  = (const float*)d_in[10];
  const float* trans = (const float*)d_in[11];
  float* out  = (float*)d_out;
  float* hbuf = (float*)d_ws;                   // 262144 floats (1 MB)
  float* em   = hbuf + 262144;                  // 2097152 floats (8 MB)

  reset_cnt_kernel<<<dim3(1), dim3(1), 0, stream>>>();

  void* args[] = { (void*)&x, (void*)&emb,
                   (void*)&Wih_f, (void*)&Whh_f, (void*)&bf,
                   (void*)&Wih_b, (void*)&Whh_b, (void*)&bb,
                   (void*)&Wout, (void*)&bout,
                   (void*)&hbuf, (void*)&em };
  hipLaunchCooperativeKernel((void*)bilstm_coop, dim3(256), dim3(512), args, 0, stream);
  viterbi_kernel<<<dim3(128), dim3(64), 0, stream>>>(em, mask, trans, out);
}

// Round 8
// 25118.370 us; speedup vs baseline: 1.4989x; 1.0804x over previous
//
#include <hip/hip_runtime.h>
#include <math.h>

namespace {
constexpr int BATCH = 128;
constexpr int SEQ   = 512;
constexpr int NL    = 32;
constexpr int BOSTAG = 1;
constexpr int EOSTAG = 2;
constexpr unsigned GRP = 128;   // blocks per barrier group (one per batch-half)
}

__device__ unsigned int g_cnt[2];

__global__ void reset_cnt_kernel() {
  __hip_atomic_store(&g_cnt[0], 0u, __ATOMIC_RELAXED, __HIP_MEMORY_SCOPE_AGENT);
  __hip_atomic_store(&g_cnt[1], 0u, __ATOMIC_RELAXED, __HIP_MEMORY_SCOPE_AGENT);
}

// Group barrier (128 blocks sharing one batch-half, both directions).
// All cross-block stores are agent-scope write-through; __syncthreads drains
// vmcnt before the counter add; acquire fence invalidates L1/L2 so cached
// reads refetch fresh lines. (r7-proven pattern, split into 2 groups.)
__device__ __forceinline__ void gbar(int ci, unsigned target) {
  __syncthreads();
  if (threadIdx.x == 0) {
    __hip_atomic_fetch_add(&g_cnt[ci], 1u, __ATOMIC_RELAXED, __HIP_MEMORY_SCOPE_AGENT);
    while (__hip_atomic_load(&g_cnt[ci], __ATOMIC_RELAXED, __HIP_MEMORY_SCOPE_AGENT) < target)
      __builtin_amdgcn_s_sleep(2);
  }
  __builtin_amdgcn_fence(__ATOMIC_ACQUIRE, "agent");
  __syncthreads();
}

// hbuf layout: [2 parity][2 dir][128 b][512 u]  (65536 floats per (par,dir))
__global__ __launch_bounds__(512, 1)
void bilstm_coop(const int* __restrict__ x,
                 const float* __restrict__ emb,
                 const float* __restrict__ Wih_f, const float* __restrict__ Whh_f, const float* __restrict__ bf,
                 const float* __restrict__ Wih_b, const float* __restrict__ Whh_b, const float* __restrict__ bbias,
                 const float* __restrict__ Wout, const float* __restrict__ bout,
                 float* __restrict__ hbuf, float* __restrict__ em)
{
  __shared__ float4 WT4[8192];     // [k(1024)][slot(8)] gates i,f,g,o in .xyzw; slot = uu ^ ((k>>2)&7). 128 KB
  __shared__ float  em_red[512];   // [kc(16)][l(32)]
  float* WTf = (float*)WT4;

  const int tid = threadIdx.x, bi = blockIdx.x;
  const int dir = bi >> 7, bidx = bi & 127;
  const int ug  = bidx >> 1, bh = bidx & 1;    // ug: 8-unit slice, bh: batch half
  const int u0  = ug * 8, b_base = bh * 64;
  const int bb  = b_base + ug;                 // emission batch owned by this block

  const float* Wih = dir ? Wih_b : Wih_f;
  const float* Whh = dir ? Whh_b : Whh_f;
  const float* bv  = dir ? bbias : bf;

  // ---- one-time: W slice -> LDS. WT4[k*8+slot] = gates of unit uu=slot^((k>>2)&7)
  for (int idx = tid; idx < 32768; idx += 512) {
    const int k = idx >> 5, r = idx & 31;
    const int gate = r & 3, uu = r >> 2;
    const int grow = gate * 512 + u0 + uu;
    const float v = (k < 512) ? Wih[(size_t)grow * 512 + k]
                              : Whh[(size_t)grow * 512 + (k - 512)];
    WTf[k * 32 + ((uu ^ ((k >> 2) & 7)) << 2) + gate] = v;
  }

  // compute roles: thread = (ks: k-split 8, ug2: unit-pair 4, bq: batch-quad 16)
  const int ks   = tid & 7;
  const int ug2  = (tid >> 3) & 3;
  const int bq   = ((tid >> 5) & 1) + 2 * (tid >> 6);   // 0..15
  const int bB   = b_base + 4 * bq;                      // first of 4 owned batches
  // W LDS float4 base indices (slot = uu^ks is constant per thread)
  const int wb0 = 32 * ks + ((2 * ug2 + 0) ^ ks);
  const int wb1 = 32 * ks + ((2 * ug2 + 1) ^ ks);
  // epilogue ownership: lane ks -> (unit n' = ks&1, batch r' = ks>>1)
  const int u_own = u0 + 2 * ug2 + (ks & 1);
  const int b_own = bB + (ks >> 1);
  // emission roles: l_ = label, kc = k-chunk of 32
  const int l_ = tid >> 4, kc = tid & 15;

  float bias_g[4];
  #pragma unroll
  for (int g = 0; g < 4; ++g) bias_g[g] = bv[g * 512 + u_own];
  float cstate = 0.f;

  // init parity-1 h: this block zeroes its own bb row (group-local dependency)
  __hip_atomic_store(&hbuf[131072 + dir * 65536 + (size_t)bb * 512 + tid], 0.f,
                     __ATOMIC_RELAXED, __HIP_MEMORY_SCOPE_AGENT);
  unsigned epoch = 1;
  gbar(bh, GRP * epoch); ++epoch;

  for (int s = 0; s < SEQ; ++s) {
    const int t = dir ? (SEQ - 1 - s) : s;

    // ---- pre-barrier: x gathers + first emb chunk (latency hidden by barrier)
    const float* e0 = emb + (size_t)x[(bB + 0) * SEQ + t] * 512 + 4 * ks;
    const float* e1 = emb + (size_t)x[(bB + 1) * SEQ + t] * 512 + 4 * ks;
    const float* e2 = emb + (size_t)x[(bB + 2) * SEQ + t] * 512 + 4 * ks;
    const float* e3 = emb + (size_t)x[(bB + 3) * SEQ + t] * 512 + 4 * ks;
    float4 cur[4], nxt[4];
    cur[0] = *(const float4*)e0; cur[1] = *(const float4*)e1;
    cur[2] = *(const float4*)e2; cur[3] = *(const float4*)e3;

    gbar(bh, GRP * epoch); ++epoch;

    const float* hprev = hbuf + (size_t)((s + 1) & 1) * 131072 + dir * 65536;
    float*       hout  = hbuf + (size_t)((s    ) & 1) * 131072 + dir * 65536;

    // ---- emission for h_{s-1}: (l_, kc) roles, coalesced Wout, 32-reg chunks
    if (s > 0) {
      const float* hb2 = hprev + (size_t)bb * 512 + kc * 32;
      const float* wr_ = Wout + (size_t)l_ * 1024 + dir * 512 + kc * 32;
      float emP = 0.f;
      #pragma unroll
      for (int h2 = 0; h2 < 2; ++h2) {
        const float4 hv0 = *(const float4*)&hb2[h2 * 16 + 0];
        const float4 hv1 = *(const float4*)&hb2[h2 * 16 + 4];
        const float4 hv2 = *(const float4*)&hb2[h2 * 16 + 8];
        const float4 hv3 = *(const float4*)&hb2[h2 * 16 + 12];
        const float4 wv0 = *(const float4*)&wr_[h2 * 16 + 0];
        const float4 wv1 = *(const float4*)&wr_[h2 * 16 + 4];
        const float4 wv2 = *(const float4*)&wr_[h2 * 16 + 8];
        const float4 wv3 = *(const float4*)&wr_[h2 * 16 + 12];
        emP = fmaf(hv0.x, wv0.x, emP); emP = fmaf(hv0.y, wv0.y, emP);
        emP = fmaf(hv0.z, wv0.z, emP); emP = fmaf(hv0.w, wv0.w, emP);
        emP = fmaf(hv1.x, wv1.x, emP); emP = fmaf(hv1.y, wv1.y, emP);
        emP = fmaf(hv1.z, wv1.z, emP); emP = fmaf(hv1.w, wv1.w, emP);
        emP = fmaf(hv2.x, wv2.x, emP); emP = fmaf(hv2.y, wv2.y, emP);
        emP = fmaf(hv2.z, wv2.z, emP); emP = fmaf(hv2.w, wv2.w, emP);
        emP = fmaf(hv3.x, wv3.x, emP); emP = fmaf(hv3.y, wv3.y, emP);
        emP = fmaf(hv3.z, wv3.z, emP); emP = fmaf(hv3.w, wv3.w, emP);
      }
      em_red[kc * 32 + l_] = emP;
    }
    __syncthreads();
    if (s > 0 && tid < 32) {
      float p = 0.f;
      #pragma unroll
      for (int ksi = 0; ksi < 16; ++ksi) p += em_red[ksi * 32 + tid];
      const int te = dir ? (SEQ - s) : (s - 1);
      const bool first = dir ? (te >= 256) : (te < 256);
      float* dst = em + ((size_t)bb * SEQ + te) * NL + tid;
      if (first) {
        __hip_atomic_store(dst, p + bout[tid], __ATOMIC_RELAXED, __HIP_MEMORY_SCOPE_AGENT);
      } else {
        const float old = *dst;
        __hip_atomic_store(dst, old + p, __ATOMIC_RELAXED, __HIP_MEMORY_SCOPE_AGENT);
      }
    }

    // ---- gate GEMM: acc[unit n][batch r][gate], R=4 x U=2, S=8 k-split ----
    float acc0[4][4], acc1[4][4];
    #pragma unroll
    for (int r = 0; r < 4; ++r)
      #pragma unroll
      for (int g = 0; g < 4; ++g) { acc0[r][g] = 0.f; acc1[r][g] = 0.f; }

    const float* h0 = hprev + (size_t)(bB + 0) * 512 + 4 * ks;
    const float* h1 = hprev + (size_t)(bB + 1) * 512 + 4 * ks;
    const float* h2 = hprev + (size_t)(bB + 2) * 512 + 4 * ks;
    const float* h3 = hprev + (size_t)(bB + 3) * 512 + 4 * ks;

    // emb half: k = 4ks + 32i + j
    #pragma unroll 2
    for (int i = 0; i < 16; ++i) {
      if (i < 15) {
        nxt[0] = *(const float4*)(e0 + (i + 1) * 32);
        nxt[1] = *(const float4*)(e1 + (i + 1) * 32);
        nxt[2] = *(const float4*)(e2 + (i + 1) * 32);
        nxt[3] = *(const float4*)(e3 + (i + 1) * 32);
      } else {
        nxt[0] = *(const float4*)h0; nxt[1] = *(const float4*)h1;
        nxt[2] = *(const float4*)h2; nxt[3] = *(const float4*)h3;
      }
      #pragma unroll
      for (int j = 0; j < 4; ++j) {
        const float4 w0 = WT4[wb0 + 256 * i + 8 * j];
        const float4 w1 = WT4[wb1 + 256 * i + 8 * j];
        #pragma unroll
        for (int r = 0; r < 4; ++r) {
          const float a = (j == 0) ? cur[r].x : (j == 1) ? cur[r].y : (j == 2) ? cur[r].z : cur[r].w;
          acc0[r][0] = fmaf(w0.x, a, acc0[r][0]);
          acc0[r][1] = fmaf(w0.y, a, acc0[r][1]);
          acc0[r][2] = fmaf(w0.z, a, acc0[r][2]);
          acc0[r][3] = fmaf(w0.w, a, acc0[r][3]);
          acc1[r][0] = fmaf(w1.x, a, acc1[r][0]);
          acc1[r][1] = fmaf(w1.y, a, acc1[r][1]);
          acc1[r][2] = fmaf(w1.z, a, acc1[r][2]);
          acc1[r][3] = fmaf(w1.w, a, acc1[r][3]);
        }
      }
      #pragma unroll
      for (int r = 0; r < 4; ++r) cur[r] = nxt[r];
    }
    // h half: k = 512 + 4ks + 32i + j
    #pragma unroll 2
    for (int i = 0; i < 16; ++i) {
      if (i < 15) {
        nxt[0] = *(const float4*)(h0 + (i + 1) * 32);
        nxt[1] = *(const float4*)(h1 + (i + 1) * 32);
        nxt[2] = *(const float4*)(h2 + (i + 1) * 32);
        nxt[3] = *(const float4*)(h3 + (i + 1) * 32);
      }
      #pragma unroll
      for (int j = 0; j < 4; ++j) {
        const float4 w0 = WT4[4096 + wb0 + 256 * i + 8 * j];
        const float4 w1 = WT4[4096 + wb1 + 256 * i + 8 * j];
        #pragma unroll
        for (int r = 0; r < 4; ++r) {
          const float a = (j == 0) ? cur[r].x : (j == 1) ? cur[r].y : (j == 2) ? cur[r].z : cur[r].w;
          acc0[r][0] = fmaf(w0.x, a, acc0[r][0]);
          acc0[r][1] = fmaf(w0.y, a, acc0[r][1]);
          acc0[r][2] = fmaf(w0.z, a, acc0[r][2]);
          acc0[r][3] = fmaf(w0.w, a, acc0[r][3]);
          acc1[r][0] = fmaf(w1.x, a, acc1[r][0]);
          acc1[r][1] = fmaf(w1.y, a, acc1[r][1]);
          acc1[r][2] = fmaf(w1.z, a, acc1[r][2]);
          acc1[r][3] = fmaf(w1.w, a, acc1[r][3]);
        }
      }
      #pragma unroll
      for (int r = 0; r < 4; ++r) cur[r] = nxt[r];
    }

    // ---- butterfly over the 8 ks lanes (xor 1,2,4) ----
    #pragma unroll
    for (int m = 1; m < 8; m <<= 1)
      #pragma unroll
      for (int r = 0; r < 4; ++r)
        #pragma unroll
        for (int g = 0; g < 4; ++g) {
          acc0[r][g] += __shfl_xor(acc0[r][g], m, 64);
          acc1[r][g] += __shfl_xor(acc1[r][g], m, 64);
        }

    // lane ks owns (unit n'=ks&1, batch r'=ks>>1): static ternary select
    {
      float g4[4];
      #pragma unroll
      for (int g = 0; g < 4; ++g) {
        float v = acc0[0][g];
        v = (ks == 1) ? acc1[0][g] : v;
        v = (ks == 2) ? acc0[1][g] : v;
        v = (ks == 3) ? acc1[1][g] : v;
        v = (ks == 4) ? acc0[2][g] : v;
        v = (ks == 5) ? acc1[2][g] : v;
        v = (ks == 6) ? acc0[3][g] : v;
        v = (ks == 7) ? acc1[3][g] : v;
        g4[g] = v;
      }
      const float gi = g4[0] + bias_g[0];
      const float gf = g4[1] + bias_g[1];
      const float gg = g4[2] + bias_g[2];
      const float go = g4[3] + bias_g[3];
      const float si = 1.f / (1.f + expf(-gi));
      const float sf = 1.f / (1.f + expf(-gf));
      const float so = 1.f / (1.f + expf(-go));
      cstate = sf * cstate + si * tanhf(gg);
      __hip_atomic_store(&hout[(size_t)b_own * 512 + u_own], so * tanhf(cstate),
                         __ATOMIC_RELAXED, __HIP_MEMORY_SCOPE_AGENT);
    }
  }
  gbar(bh, GRP * epoch); ++epoch;

  // ---- tail emission for the last h (parity 1) ----
  {
    const float* hb2 = hbuf + 131072 + dir * 65536 + (size_t)bb * 512 + kc * 32;
    const float* wr_ = Wout + (size_t)l_ * 1024 + dir * 512 + kc * 32;
    float emP = 0.f;
    #pragma unroll
    for (int h2 = 0; h2 < 2; ++h2) {
      #pragma unroll
      for (int q = 0; q < 4; ++q) {
        const float4 hv = *(const float4*)&hb2[h2 * 16 + q * 4];
        const float4 wv = *(const float4*)&wr_[h2 * 16 + q * 4];
        emP = fmaf(hv.x, wv.x, emP); emP = fmaf(hv.y, wv.y, emP);
        emP = fmaf(hv.z, wv.z, emP); emP = fmaf(hv.w, wv.w, emP);
      }
    }
    em_red[kc * 32 + l_] = emP;
    __syncthreads();
    if (tid < 32) {
      float p = 0.f;
      #pragma unroll
      for (int ksi = 0; ksi < 16; ++ksi) p += em_red[ksi * 32 + tid];
      const int te = dir ? 0 : (SEQ - 1);
      float* dst = em + ((size_t)bb * SEQ + te) * NL + tid;
      const float old = *dst;
      __hip_atomic_store(dst, old + p, __ATOMIC_RELAXED, __HIP_MEMORY_SCOPE_AGENT);
    }
  }
}

__global__ __launch_bounds__(64)
void viterbi_kernel(const float* __restrict__ em, const int* __restrict__ mask,
                    const float* __restrict__ trans, float* __restrict__ out)
{
  __shared__ float tr[32][33];
  __shared__ float alpha[32];
  __shared__ float fin[32];
  __shared__ unsigned char bp[SEQ][32];
  __shared__ float path[SEQ];

  const int b = blockIdx.x, tid = threadIdx.x;
  for (int i = tid; i < 1024; i += 64) tr[i >> 5][i & 31] = trans[i];
  __syncthreads();

  const float* emB = em + (size_t)b * SEQ * NL;
  if (tid < 32) alpha[tid] = tr[BOSTAG][tid] + emB[tid];
  __syncthreads();

  for (int t = 1; t < SEQ; ++t) {
    float best = -INFINITY, e = 0.f;
    int arg = 0;
    if (tid < 32) {
      e = emB[t * NL + tid];
      #pragma unroll 4
      for (int p = 0; p < 32; ++p) {
        const float sc = (alpha[p] + tr[p][tid]) + e;  // np broadcast order
        if (sc > best) { best = sc; arg = p; }          // first-occurrence argmax
      }
    }
    __syncthreads();
    if (tid < 32) {
      const float m = (float)mask[b * SEQ + t];
      alpha[tid] = m * best + (1.f - m) * alpha[tid];
      bp[t][tid] = (unsigned char)arg;
    }
    __syncthreads();
  }

  if (tid < 32) fin[tid] = alpha[tid] + tr[tid][EOSTAG];
  __syncthreads();

  if (tid == 0) {
    float best = fin[0]; int tag = 0;
    for (int n = 1; n < 32; ++n) if (fin[n] > best) { best = fin[n]; tag = n; }
    out[b] = best;
    path[SEQ - 1] = (float)tag;
    for (int k = SEQ - 2; k >= 0; --k) {
      const int prev = bp[k + 1][tag];
      if (mask[b * SEQ + k + 1] > 0) tag = prev;
      path[k] = (float)tag;
    }
  }
  __syncthreads();
  for (int idx = tid; idx < SEQ; idx += 64)
    out[BATCH + (size_t)b * SEQ + idx] = path[idx];
}

extern "C" void kernel_launch(void* const* d_in, const int* in_sizes, int n_in,
                              void* d_out, int out_size, void* d_ws, size_t ws_size,
                              hipStream_t stream) {
  (void)in_sizes; (void)n_in; (void)out_size; (void)ws_size;
  const int*   x     = (const int*)d_in[0];
  const int*   mask  = (const int*)d_in[1];
  const float* emb   = (const float*)d_in[2];
  const float* Wih_f = (const float*)d_in[3];
  const float* Whh_f = (const float*)d_in[4];
  const float* bf    = (const float*)d_in[5];
  const float* Wih_b = (const float*)d_in[6];
  const float* Whh_b = (const float*)d_in[7];
  const float* bb    = (const float*)d_in[8];
  const float* Wout  = (const float*)d_in[9];
  const float* bout  = (const float*)d_in[10];
  const float* trans = (const float*)d_in[11];
  float* out  = (float*)d_out;
  float* hbuf = (float*)d_ws;                   // 262144 floats (1 MB)
  float* em   = hbuf + 262144;                  // 2097152 floats (8 MB)

  reset_cnt_kernel<<<dim3(1), dim3(1), 0, stream>>>();

  void* args[] = { (void*)&x, (void*)&emb,
                   (void*)&Wih_f, (void*)&Whh_f, (void*)&bf,
                   (void*)&Wih_b, (void*)&Whh_b, (void*)&bb,
                   (void*)&Wout, (void*)&bout,
                   (void*)&hbuf, (void*)&em };
  hipLaunchCooperativeKernel((void*)bilstm_coop, dim3(256), dim3(512), args, 0, stream);
  viterbi_kernel<<<dim3(128), dim3(64), 0, stream>>>(em, mask, trans, out);
}